// Round 6
// baseline (347.887 us; speedup 1.0000x reference)
//
#include <hip/hip_runtime.h>
#include <hip/hip_bf16.h>

// SRU cell, fp32 in / fp32 out (internal bf16 MFMA GEMM).
// L=1024, B=32, d=512. M=32768 (reordered m=b*1024+t), K=512, N=1536.
// ws: xr (bf16 [b][t][k], 32MB) | wt (bf16 [n][k], 1.5MB) | u (bf16 [gate][bj][t], 96MB)

typedef __attribute__((ext_vector_type(8))) __bf16 bf16x8;
typedef __attribute__((ext_vector_type(4))) __bf16 bf16x4;
typedef __attribute__((ext_vector_type(4))) float floatx4;
typedef __attribute__((ext_vector_type(4))) unsigned int uint4v;

#define LOG2E 1.4426950408889634f

// ---- x[t][b][k] fp32 -> xr[b][t][k] bf16 (row-gather copy, both sides coalesced)
__global__ __launch_bounds__(256) void cvt_x(const float* __restrict__ x,
                                             __bf16* __restrict__ xr) {
  const int t = threadIdx.x;
  const int r0 = blockIdx.x * 8;  // 4096 blocks x 8 rows
#pragma unroll
  for (int q = 0; q < 4; ++q) {
    int fid = q * 256 + t;        // 0..1023: row = fid>>7, float4-col = fid&127
    int R = r0 + (fid >> 7);      // global row = tt*32 + b
    int cc = fid & 127;
    float4 v = *(const float4*)(x + (size_t)R * 512 + cc * 4);
    int b = R & 31, tt = R >> 5;
    bf16x4 o = {(__bf16)v.x, (__bf16)v.y, (__bf16)v.z, (__bf16)v.w};
    *(bf16x4*)(xr + (size_t)(b * 1024 + tt) * 512 + cc * 4) = o;
  }
}

// ---- w[k][n] fp32 -> wt[n][k] bf16, LDS tile transpose (coalesced both sides)
__global__ __launch_bounds__(256) void cvt_w(const float* __restrict__ w,
                                             __bf16* __restrict__ wt) {
  __shared__ __bf16 tile[64][68];
  const int k0 = blockIdx.x * 64, n0 = blockIdx.y * 64;
  const int t = threadIdx.x;
  const int nl = t & 63, kq = t >> 6;
#pragma unroll
  for (int r = 0; r < 16; ++r) {
    int kl = r * 4 + kq;
    tile[nl][kl] = (__bf16)w[(size_t)(k0 + kl) * 1536 + n0 + nl];
  }
  __syncthreads();
  const int kl2 = t & 63, nq = t >> 6;
#pragma unroll
  for (int r = 0; r < 16; ++r) {
    int nl2 = r * 4 + nq;
    wt[(size_t)(n0 + nl2) * 512 + k0 + kl2] = tile[nl2][kl2];
  }
}

// ---- GEMM: barrier-free K-loop. A-tile (64x512) resident in LDS (staged once
// via swizzled-source global_load_lds); B fragments in registers, reloaded in
// 4 quarter-K phases (64 VGPR each). 16 MFMA per 4 ds_read_b128. Epilogue
// stores u in scan-native layout u[gate][b*512+j][t] (packed 8B stores).
__global__ __launch_bounds__(256, 2) void gemm_kernel(const __bf16* __restrict__ A,
                                                      const __bf16* __restrict__ Bt,
                                                      __bf16* __restrict__ U) {
  __shared__ __attribute__((aligned(16))) __bf16 As[64 * 512];  // 64KB
  const int mb = blockIdx.x;  // 0..511: b = mb>>4, t0 = (mb&15)*64
  const int nt = blockIdx.y;  // 0..5
  const int tid = threadIdx.x;
  const int wave = tid >> 6, lane = tid & 63;
  const int quad = lane >> 4, l16 = lane & 15;
  const int m0 = mb * 64;
  const int nw = nt * 256 + wave * 64;  // wave's first col

  // stage A once: instr (wave,q) fills row m = wave*16+q; source chunks
  // permuted so LDS position csw holds logical chunk c, csw=(c&~7)|((c&7)^(m&7))
  {
    const __bf16* rowbase = A + (size_t)m0 * 512;
#pragma unroll
    for (int q = 0; q < 16; ++q) {
      int m = wave * 16 + q;
      int csrc = (lane & ~7) | ((lane & 7) ^ (m & 7));
      const __bf16* src = rowbase + m * 512 + csrc * 8;
      __builtin_amdgcn_global_load_lds(
          (const __attribute__((address_space(1))) void*)src,
          (__attribute__((address_space(3))) void*)(As + m * 512), 16, 0, 0);
    }
  }

  floatx4 acc[4][4] = {};
  bf16x8 bfrag[4][4];  // [k-window within phase][n-subtile]

  // preload B phase 0 while A staging drains
#pragma unroll
  for (int kq = 0; kq < 4; ++kq)
#pragma unroll
    for (int ns = 0; ns < 4; ++ns)
      bfrag[kq][ns] = *(const bf16x8*)(Bt + (size_t)(nw + ns * 16 + l16) * 512 +
                                       kq * 32 + quad * 8);
  __syncthreads();  // A resident from here; no further barriers

  for (int ph = 0; ph < 4; ++ph) {
    if (ph > 0) {
#pragma unroll
      for (int kq = 0; kq < 4; ++kq)
#pragma unroll
        for (int ns = 0; ns < 4; ++ns)
          bfrag[kq][ns] = *(const bf16x8*)(Bt + (size_t)(nw + ns * 16 + l16) * 512 +
                                           (ph * 4 + kq) * 32 + quad * 8);
    }
#pragma unroll
    for (int kq = 0; kq < 4; ++kq) {
      const int kw = ph * 4 + kq;
      bf16x8 af[4];
#pragma unroll
      for (int mt = 0; mt < 4; ++mt) {
        int m = mt * 16 + l16;
        int c = kw * 4 + quad;
        int csw = (c & ~7) | ((c & 7) ^ (m & 7));
        af[mt] = *(const bf16x8*)(As + m * 512 + csw * 8);
      }
#pragma unroll
      for (int mt = 0; mt < 4; ++mt)
#pragma unroll
        for (int ns = 0; ns < 4; ++ns)
          acc[mt][ns] = __builtin_amdgcn_mfma_f32_16x16x32_bf16(
              af[mt], bfrag[kq][ns], acc[mt][ns], 0, 0, 0);
    }
  }

  // epilogue: C/D row=quad*4+i (consecutive t!), col=l16. Pack 4 t's -> 8B store.
  const int b = mb >> 4, t0 = (mb & 15) * 64;
#pragma unroll
  for (int mt = 0; mt < 4; ++mt)
#pragma unroll
    for (int ns = 0; ns < 4; ++ns) {
      int n = nw + ns * 16 + l16;
      int gate = n >> 9, j = n & 511;
      int tt = t0 + mt * 16 + quad * 4;
      bf16x4 o = {(__bf16)acc[mt][ns][0], (__bf16)acc[mt][ns][1],
                  (__bf16)acc[mt][ns][2], (__bf16)acc[mt][ns][3]};
      *(bf16x4*)(U + (size_t)(gate * 16384 + b * 512 + j) * 1024 + tt) = o;
    }
}

// ---- SRU scan: dense per-lane u streams (u[gate][bj][t]), depth-4 rotation ---
// 256 blocks x 64 thr (1 wave/CU). Per 8-step group: 3 b128 u-loads (per-lane
// sequential streams, L1 absorbs line sharing) + 8 coalesced x dwords; issue
// distance 4 groups keeps ~20KB/CU in flight (HBM latency x BW ~ 9KB).
__global__ __launch_bounds__(64, 1) void scan_kernel(
    const __bf16* __restrict__ u, const float* __restrict__ x,
    const float* __restrict__ wc, const float* __restrict__ bias,
    const float* __restrict__ c0, float* __restrict__ out) {
  const int bj = blockIdx.x * 64 + threadIdx.x;
  const int j = bj & 511;
  const float vf = wc[j], vr = wc[512 + j];
  const float bfv = bias[j], brv = bias[512 + j];
  const float nvf = -vf * LOG2E, nvr = -vr * LOG2E;
  const float pbf = -bfv * LOG2E, pbr = -brv * LOG2E;
  const float n2 = -2.f * LOG2E;
  float c = c0[bj];

  const __bf16* u0p = u + (size_t)bj * 1024;
  const __bf16* u1p = u0p + (size_t)16384 * 1024;
  const __bf16* u2p = u1p + (size_t)16384 * 1024;
  const float* xp = x + bj;

  uint4v b0[4], b1[4], b2[4];
  float xb[4][8];

#pragma unroll
  for (int d = 0; d < 4; ++d) {
    b0[d] = *(const uint4v*)(u0p + d * 8);
    b1[d] = *(const uint4v*)(u1p + d * 8);
    b2[d] = *(const uint4v*)(u2p + d * 8);
#pragma unroll
    for (int i = 0; i < 8; ++i) xb[d][i] = xp[(size_t)(d * 8 + i) * 16384];
  }

  for (int it = 0; it < 32; ++it) {
#pragma unroll
    for (int sub = 0; sub < 4; ++sub) {
      const int g = it * 4 + sub;
      const uint4v v0 = b0[sub], v1 = b1[sub], v2 = b2[sub];
      float* op = out + (size_t)g * 8 * 16384 + bj;
#pragma unroll
      for (int i = 0; i < 8; ++i) {
        unsigned w0 = v0[i >> 1], w1 = v1[i >> 1], w2 = v2[i >> 1];
        float u0 = __builtin_bit_cast(float, (i & 1) ? (w0 & 0xffff0000u) : (w0 << 16));
        float u1 = __builtin_bit_cast(float, (i & 1) ? (w1 & 0xffff0000u) : (w1 << 16));
        float u2 = __builtin_bit_cast(float, (i & 1) ? (w2 & 0xffff0000u) : (w2 << 16));
        float a1 = __builtin_fmaf(nvf, c, __builtin_fmaf(u1, -LOG2E, pbf));
        float f = __builtin_amdgcn_rcpf(1.f + __builtin_exp2f(a1));
        c = __builtin_fmaf(f, c - u0, u0);
        float a2 = __builtin_fmaf(nvr, c, __builtin_fmaf(u2, -LOG2E, pbr));
        float r = __builtin_amdgcn_rcpf(1.f + __builtin_exp2f(a2));
        float tg = __builtin_amdgcn_rcpf(1.f + __builtin_exp2f(c * n2));
        float gg = __builtin_fmaf(2.f, tg, -1.f);  // tanh(c)
        float xs = xb[sub][i] * 1.7320508075688772f;
        float h = __builtin_fmaf(r, gg - xs, xs);
        op[(size_t)i * 16384] = h;
      }
      int gn = g + 4;
      if (gn > 127) gn = 127;  // clamped redundant loads, branch-free
      b0[sub] = *(const uint4v*)(u0p + gn * 8);
      b1[sub] = *(const uint4v*)(u1p + gn * 8);
      b2[sub] = *(const uint4v*)(u2p + gn * 8);
#pragma unroll
      for (int i = 0; i < 8; ++i) xb[sub][i] = xp[(size_t)(gn * 8 + i) * 16384];
    }
  }
  out[(size_t)16777216 + bj] = c;  // c_last
}

extern "C" void kernel_launch(void* const* d_in, const int* in_sizes, int n_in,
                              void* d_out, int out_size, void* d_ws, size_t ws_size,
                              hipStream_t stream) {
  const float* x = (const float*)d_in[0];     // (1024,32,512) fp32
  const float* w = (const float*)d_in[1];     // (512,1536)    fp32
  const float* wc = (const float*)d_in[2];    // (1024,)       fp32
  const float* bias = (const float*)d_in[3];  // (1024,)       fp32
  const float* c0 = (const float*)d_in[4];    // (32,512)      fp32
  float* out = (float*)d_out;                 // h (L,B,d) | c_last (B,d)

  char* ws = (char*)d_ws;
  __bf16* xr = (__bf16*)ws;                        // 33,554,432 B
  __bf16* wt = (__bf16*)(ws + 33554432);           //  1,572,864 B
  __bf16* u = (__bf16*)(ws + 33554432 + 1572864);  // 100,663,296 B

  cvt_x<<<4096, 256, 0, stream>>>(x, xr);
  cvt_w<<<dim3(8, 24), 256, 0, stream>>>(w, wt);
  gemm_kernel<<<dim3(512, 6), 256, 0, stream>>>(xr, wt, u);
  scan_kernel<<<256, 64, 0, stream>>>(u, x, wc, bias, c0, out);
}